// Round 2
// baseline (527.773 us; speedup 1.0000x reference)
//
#include <hip/hip_runtime.h>
#include <hip/hip_bf16.h>

// MHA pipeline, all-bf16 MFMA (fp32 accum):
//   cvt(+scale wq by log2e/8) ; pack mask to bits ;
//   gemm Q,K (head-split layout) ; gemm V (transposed layout) ;
//   fused flash attention (S^T = K*Q^T trick, exp2 domain) ;
//   gemm out (fp32 output).

typedef __attribute__((ext_vector_type(8))) short short8;   // bf16x8 MFMA frag
typedef __attribute__((ext_vector_type(4))) float f32x4;
typedef __attribute__((ext_vector_type(4))) unsigned int u32x4;
typedef unsigned short u16;
typedef unsigned int u32;
typedef unsigned long long u64;

#define GLD16(gp, lp) __builtin_amdgcn_global_load_lds( \
    (const __attribute__((address_space(1))) void*)(gp), \
    (__attribute__((address_space(3))) void*)(lp), 16, 0, 0)

#if __has_builtin(__builtin_amdgcn_exp2f)
#define EXP2F(x) __builtin_amdgcn_exp2f(x)
#else
#define EXP2F(x) exp2f(x)
#endif

__device__ __forceinline__ u16 f2bf(float f) {            // RNE fp32->bf16
  u32 u = __builtin_bit_cast(u32, f);
  return (u16)((u + 0x7FFFu + ((u >> 16) & 1u)) >> 16);
}
// XOR swizzles (involutions): 64B-row tiles and 128B-row tiles.
__device__ __forceinline__ u32 swz64(u32 b)  { return b ^ (((b >> 7) & 3u) << 4); }
__device__ __forceinline__ u32 swz128(u32 b) { return b ^ (((b >> 7) & 7u) << 4); }

// ---------------- fp32 -> bf16 convert (vectorized, 8 elem/thread) ----------
__global__ __launch_bounds__(256) void cvt_kernel(const float* __restrict__ in,
                                                  u16* __restrict__ out, float scale) {
  const size_t i = (size_t)blockIdx.x * 256 + threadIdx.x;
  f32x4 a = *(const f32x4*)(in + i * 8);
  f32x4 b = *(const f32x4*)(in + i * 8 + 4);
  u32x4 w;
  w.x = (u32)f2bf(a[0] * scale) | ((u32)f2bf(a[1] * scale) << 16);
  w.y = (u32)f2bf(a[2] * scale) | ((u32)f2bf(a[3] * scale) << 16);
  w.z = (u32)f2bf(b[0] * scale) | ((u32)f2bf(b[1] * scale) << 16);
  w.w = (u32)f2bf(b[2] * scale) | ((u32)f2bf(b[3] * scale) << 16);
  *(u32x4*)(out + i * 8) = w;
}

// ---------------- mask (int32 0/1) -> packed bits (bit=1 means masked) ------
__global__ __launch_bounds__(256) void pack_mask_kernel(const int* __restrict__ m,
                                                        u64* __restrict__ out) {
  const size_t i = (size_t)blockIdx.x * 256 + threadIdx.x;
  u64 bal = __ballot(m[i] == 1);
  if ((threadIdx.x & 63) == 0) out[i >> 6] = bal;
}

// ---------------- GEMM: C[M=8192][N=1024] = A[M][K] * W[N][K]^T, bf16 -------
// 128x128 tile, BK=32, 4 waves (each 64x64), 16x16x32 bf16 MFMA.
// MODE 0: bf16 head-split  Qh[((b*16+h)*2048+s)*64+d]
// MODE 1: bf16 transposed  Vt[((b*16+h)*64+d)*2048+s]
// MODE 2: fp32 row-major   out[m*1024+n]
template <int MODE>
__global__ __launch_bounds__(256)
void gemm_bt(const u16* __restrict__ A, const u16* __restrict__ W,
             void* __restrict__ outp, int K_) {
  __shared__ alignas(16) char sm[16384];          // A-tile 8K | W-tile 8K
  const int tid = threadIdx.x, lane = tid & 63, wid = tid >> 6;
  const int g = lane >> 4, ln16 = lane & 15;
  const int wr = wid >> 1, wc = wid & 1;
  const int bm = blockIdx.y * 128, bn = blockIdx.x * 128;
  const int ldb = K_ * 2;

  u32 aoff[4], boff[4];
#pragma unroll
  for (int t = 0; t < 4; ++t) {
    aoff[t] = swz64(((u32)(wr * 64 + t * 16 + ln16) << 6) + ((u32)g << 4));
    boff[t] = 8192u + swz64(((u32)(wc * 64 + t * 16 + ln16) << 6) + ((u32)g << 4));
  }
  // staging: linear LDS dest, source pre-permuted through the swizzle involution
  const char* ga[2]; const char* gw[2]; u32 doff[2];
#pragma unroll
  for (int i = 0; i < 2; ++i) {
    u32 lb = swz64((u32)(tid + i * 256) << 4);
    u32 row = lb >> 6, kbyte = lb & 63;
    ga[i] = (const char*)A + (size_t)(bm + row) * ldb + kbyte;
    gw[i] = (const char*)W + (size_t)(bn + row) * ldb + kbyte;
    doff[i] = (u32)(wid * 1024 + i * 4096);
  }
  f32x4 acc[4][4] = {};
  const int nk = K_ >> 5;
  for (int kt = 0; kt < nk; ++kt) {
    __syncthreads();
#pragma unroll
    for (int i = 0; i < 2; ++i) {
      GLD16(ga[i], sm + doff[i]);
      GLD16(gw[i], sm + 8192 + doff[i]);
      ga[i] += 64; gw[i] += 64;
    }
    __syncthreads();
    short8 aF[4], bF[4];
#pragma unroll
    for (int t = 0; t < 4; ++t) aF[t] = *(const short8*)(sm + aoff[t]);
#pragma unroll
    for (int t = 0; t < 4; ++t) bF[t] = *(const short8*)(sm + boff[t]);
#pragma unroll
    for (int mt = 0; mt < 4; ++mt)
#pragma unroll
      for (int nt = 0; nt < 4; ++nt)
        acc[mt][nt] = __builtin_amdgcn_mfma_f32_16x16x32_bf16(aF[mt], bF[nt], acc[mt][nt], 0, 0, 0);
  }
  // epilogue: C frag layout col=lane&15, row=(lane>>4)*4+reg  [m89-verified]
#pragma unroll
  for (int mt = 0; mt < 4; ++mt)
#pragma unroll
    for (int nt = 0; nt < 4; ++nt) {
      const f32x4 v = acc[mt][nt];
      const int row0 = bm + wr * 64 + mt * 16 + g * 4;
      const int col = bn + wc * 64 + nt * 16 + ln16;
      if (MODE == 2) {
        float* o = (float*)outp;
#pragma unroll
        for (int r = 0; r < 4; ++r) o[(size_t)(row0 + r) * 1024 + col] = v[r];
      } else if (MODE == 0) {
        u16* o = (u16*)outp;
        const int h = col >> 6, d = col & 63;
#pragma unroll
        for (int r = 0; r < 4; ++r) {
          const int row = row0 + r, b = row >> 11, s = row & 2047;
          o[((size_t)(b * 16 + h) * 2048 + s) * 64 + d] = f2bf(v[r]);
        }
      } else {  // MODE 1: transposed V; 4 regs = 4 consecutive s -> one 8B store
        u16* o = (u16*)outp;
        const int h = col >> 6, d = col & 63;
        const int b = row0 >> 11, s = row0 & 2047;
        u64 pv = (u64)f2bf(v[0]) | ((u64)f2bf(v[1]) << 16) |
                 ((u64)f2bf(v[2]) << 32) | ((u64)f2bf(v[3]) << 48);
        *(u64*)&o[((size_t)(b * 16 + h) * 64 + d) * 2048 + s] = pv;
      }
    }
}

// ---------------- fused flash attention -------------------------------------
// Block: (qblk, h, b), 128 q-rows, 4 waves (32 q each). KV-tile = 64.
// S^T = mfma(A=K, B=Q^T)  -> D: row=k, col=q  (both operands d-contiguous)
// O^T = mfma(A=V^T, B=P^T) with P bounced through wave-private LDS.
// exp2 domain (log2e/8 pre-folded into wq). Masked scores excluded from sum
// (p=0) but raw max is used: softmax is shift-invariant so result identical.
__global__ __launch_bounds__(256)
void attn_kernel(const u16* __restrict__ Qh, const u16* __restrict__ Kh,
                 const u16* __restrict__ Vt, const u64* __restrict__ mp,
                 u16* __restrict__ AO) {
  __shared__ alignas(16) char sm[32768];  // Ks 8K | Vs 8K | P 4x4K (wave-private)
  const int tid = threadIdx.x, lane = tid & 63, wid = tid >> 6;
  const int g = lane >> 4, ln16 = lane & 15;
  char* Pl = sm + 16384 + wid * 4096;
  const int h = blockIdx.y, b = blockIdx.z;
  const int bh = b * 16 + h;
  const int q0 = blockIdx.x * 128 + wid * 32;
  const u16* Qb = Qh + (size_t)bh * 2048 * 64;
  const char* Kb = (const char*)Kh + (size_t)bh * 2048 * 128;
  const char* Vb = (const char*)Vt + (size_t)bh * 64 * 4096;

  short8 qf[2][2];  // hoisted Q B-frags: B[d][q], lane: q=ln16, d=s*32+g*8..+8
#pragma unroll
  for (int qs = 0; qs < 2; ++qs)
#pragma unroll
    for (int s = 0; s < 2; ++s)
      qf[qs][s] = *(const short8*)(Qb + (size_t)(q0 + qs * 16 + ln16) * 64 + s * 32 + g * 8);

  f32x4 acc[2][4] = {};
  float mx[2] = {-1e30f, -1e30f};
  float ls[2] = {0.f, 0.f};

  u32 srow[2], sbyt[2];
#pragma unroll
  for (int i = 0; i < 2; ++i) {
    u32 lb = swz128((u32)(tid + i * 256) << 4);
    srow[i] = lb >> 7; sbyt[i] = lb & 127;
  }
  const u64* mq = mp + ((size_t)b * 2048 + q0 + ln16) * 32;

  for (int kv = 0; kv < 2048; kv += 64) {
    __syncthreads();
#pragma unroll
    for (int i = 0; i < 2; ++i) {
      const u32 doff = (u32)(wid * 1024 + i * 4096);
      GLD16(Kb + (size_t)(kv + srow[i]) * 128 + sbyt[i], sm + doff);
      GLD16(Vb + (size_t)srow[i] * 4096 + (size_t)kv * 2 + sbyt[i], sm + 8192 + doff);
    }
    __syncthreads();

    u64 mw0 = mq[kv >> 6];
    u64 mw1 = mq[512 + (kv >> 6)];

    f32x4 sc[2][4] = {};
#pragma unroll
    for (int s = 0; s < 2; ++s)
#pragma unroll
      for (int kt = 0; kt < 4; ++kt) {
        short8 kf = *(const short8*)(sm + swz128(((u32)(kt * 16 + ln16) << 7) + s * 64 + g * 16));
        sc[0][kt] = __builtin_amdgcn_mfma_f32_16x16x32_bf16(kf, qf[0][s], sc[0][kt], 0, 0, 0);
        sc[1][kt] = __builtin_amdgcn_mfma_f32_16x16x32_bf16(kf, qf[1][s], sc[1][kt], 0, 0, 0);
      }

#pragma unroll
    for (int qs = 0; qs < 2; ++qs) {
      const u64 mw = qs ? mw1 : mw0;
      float tm = sc[qs][0][0];
#pragma unroll
      for (int kt = 0; kt < 4; ++kt)
#pragma unroll
        for (int r = 0; r < 4; ++r) tm = fmaxf(tm, sc[qs][kt][r]);
      tm = fmaxf(tm, __shfl_xor(tm, 16, 64));
      tm = fmaxf(tm, __shfl_xor(tm, 32, 64));
      const float mn = fmaxf(mx[qs], tm);
      const float corr = EXP2F(mx[qs] - mn);
      mx[qs] = mn;
      const u32 lo = (u32)mw, hi = (u32)(mw >> 32);
      float ps = 0.f;
#pragma unroll
      for (int kt = 0; kt < 4; ++kt) {
        const u32 nib = (((kt < 2) ? lo : hi) >> ((kt & 1) * 16 + g * 4)) & 0xFu;
        u64 pv = 0;
#pragma unroll
        for (int r = 0; r < 4; ++r) {
          float p = EXP2F(sc[qs][kt][r] - mn);
          if (nib & (1u << r)) p = 0.f;
          ps += p;
          pv |= (u64)f2bf(p) << (16 * r);
        }
        // P[q][k], 4 consecutive k per lane -> b64; swizzled 128B rows
        *(u64*)(Pl + swz128(((u32)(qs * 16 + ln16) << 7) + (u32)(kt * 32 + g * 8))) = pv;
      }
      ps += __shfl_xor(ps, 16, 64);
      ps += __shfl_xor(ps, 32, 64);
      ls[qs] = ls[qs] * corr + ps;
#pragma unroll
      for (int dt = 0; dt < 4; ++dt) acc[qs][dt] = acc[qs][dt] * corr;
    }
    asm volatile("" ::: "memory");  // order P writes before PV reads (same wave, DS in-order)

#pragma unroll
    for (int s = 0; s < 2; ++s) {
      short8 pf0 = *(const short8*)(Pl + swz128(((u32)ln16 << 7) + s * 64 + g * 16));
      short8 pf1 = *(const short8*)(Pl + swz128(((u32)(16 + ln16) << 7) + s * 64 + g * 16));
#pragma unroll
      for (int dt = 0; dt < 4; ++dt) {
        short8 vf = *(const short8*)(sm + 8192 + swz128(((u32)(dt * 16 + ln16) << 7) + s * 64 + g * 16));
        acc[0][dt] = __builtin_amdgcn_mfma_f32_16x16x32_bf16(vf, pf0, acc[0][dt], 0, 0, 0);
        acc[1][dt] = __builtin_amdgcn_mfma_f32_16x16x32_bf16(vf, pf1, acc[1][dt], 0, 0, 0);
      }
    }
    asm volatile("" ::: "memory");  // keep next-iter P writes after these reads
  }

#pragma unroll
  for (int qs = 0; qs < 2; ++qs) {
    const float rl = 1.0f / ls[qs];
    const int q = q0 + qs * 16 + ln16;
#pragma unroll
    for (int dt = 0; dt < 4; ++dt) {
      const f32x4 v = acc[qs][dt];
      u64 pv = (u64)f2bf(v[0] * rl) | ((u64)f2bf(v[1] * rl) << 16) |
               ((u64)f2bf(v[2] * rl) << 32) | ((u64)f2bf(v[3] * rl) << 48);
      *(u64*)(AO + ((size_t)b * 2048 + q) * 1024 + h * 64 + dt * 16 + g * 4) = pv;
    }
  }
}

// ---------------------------------------------------------------------------
extern "C" void kernel_launch(void* const* d_in, const int* in_sizes, int n_in,
                              void* d_out, int out_size, void* d_ws, size_t ws_size,
                              hipStream_t stream) {
  const float* q   = (const float*)d_in[0];
  const float* k   = (const float*)d_in[1];
  const float* v   = (const float*)d_in[2];
  const int*   msk = (const int*)d_in[3];
  const float* wq  = (const float*)d_in[4];
  const float* wk  = (const float*)d_in[5];
  const float* wv  = (const float*)d_in[6];
  const float* wo  = (const float*)d_in[7];

  char* ws = (char*)d_ws;
  const size_t SZX = (size_t)8192 * 1024 * 2;  // 16 MiB activation (bf16)
  const size_t SZW = (size_t)1024 * 1024 * 2;  // 2 MiB weight (bf16)
  u16* qb  = (u16*)(ws + 0 * SZX);
  u16* kb  = (u16*)(ws + 1 * SZX);
  u16* vb  = (u16*)(ws + 2 * SZX);
  u16* wqb = (u16*)(ws + 3 * SZX + 0 * SZW);
  u16* wkb = (u16*)(ws + 3 * SZX + 1 * SZW);
  u16* wvb = (u16*)(ws + 3 * SZX + 2 * SZW);
  u16* wob = (u16*)(ws + 3 * SZX + 3 * SZW);
  u16* Qh  = (u16*)(ws + 3 * SZX + 4 * SZW);
  u16* Kh  = (u16*)(ws + 4 * SZX + 4 * SZW);
  u16* Vtp = (u16*)(ws + 5 * SZX + 4 * SZW);
  u16* AO  = qb;                               // alias: qb dead after Q GEMM
  u64* mp  = (u64*)(ws + 6 * SZX + 4 * SZW);   // peak ~106 MiB

  const float QSCALE = 0.18033688011112042f;  // log2(e) / sqrt(64)

  cvt_kernel<<<4096, 256, 0, stream>>>(q, qb, 1.0f);
  cvt_kernel<<<4096, 256, 0, stream>>>(k, kb, 1.0f);
  cvt_kernel<<<4096, 256, 0, stream>>>(v, vb, 1.0f);
  cvt_kernel<<<512, 256, 0, stream>>>(wq, wqb, QSCALE);
  cvt_kernel<<<512, 256, 0, stream>>>(wk, wkb, 1.0f);
  cvt_kernel<<<512, 256, 0, stream>>>(wv, wvb, 1.0f);
  cvt_kernel<<<512, 256, 0, stream>>>(wo, wob, 1.0f);
  pack_mask_kernel<<<65536, 256, 0, stream>>>(msk, mp);

  gemm_bt<0><<<dim3(8, 64), 256, 0, stream>>>(qb, wqb, (void*)Qh, 1024);
  gemm_bt<0><<<dim3(8, 64), 256, 0, stream>>>(kb, wkb, (void*)Kh, 1024);
  gemm_bt<1><<<dim3(8, 64), 256, 0, stream>>>(vb, wvb, (void*)Vtp, 1024);

  attn_kernel<<<dim3(16, 16, 4), 256, 0, stream>>>(Qh, Kh, Vtp, mp, AO);

  gemm_bt<2><<<dim3(8, 64), 256, 0, stream>>>(AO, wob, d_out, 1024);
}

// Round 9
// 456.497 us; speedup vs baseline: 1.1561x; 1.1561x over previous
//
#include <hip/hip_runtime.h>
#include <hip/hip_bf16.h>

// MHA pipeline, all-bf16 MFMA (fp32 accum):
//   cvt(+scale wq by log2e/8) ; pack mask to bits ;
//   gemm Q,K (head-split) ; gemm V (transposed) ;
//   fused flash attention (S^T = K*Q^T, lane-local P via 16x16x16 PV, dbuf KV) ;
//   gemm out (fp32 output).

typedef __attribute__((ext_vector_type(8))) short short8;   // bf16x8 (4 VGPR)
typedef __attribute__((ext_vector_type(4))) short s16x4;    // bf16x4 (2 VGPR)
typedef __attribute__((ext_vector_type(4))) float f32x4;
typedef __attribute__((ext_vector_type(2))) unsigned int u32x2;
typedef __attribute__((ext_vector_type(4))) unsigned int u32x4;
typedef unsigned short u16;
typedef unsigned int u32;
typedef unsigned long long u64;

#define GLD16(gp, lp) __builtin_amdgcn_global_load_lds( \
    (const __attribute__((address_space(1))) void*)(gp), \
    (__attribute__((address_space(3))) void*)(lp), 16, 0, 0)

#if __has_builtin(__builtin_amdgcn_exp2f)
#define EXP2F(x) __builtin_amdgcn_exp2f(x)
#else
#define EXP2F(x) exp2f(x)
#endif

#define MFMA32(a, b, c) __builtin_amdgcn_mfma_f32_16x16x32_bf16(a, b, c, 0, 0, 0)

#if __has_builtin(__builtin_amdgcn_mfma_f32_16x16x16bf16_1k)
__device__ __forceinline__ f32x4 mfma16(s16x4 a, s16x4 b, f32x4 c) {
  return __builtin_amdgcn_mfma_f32_16x16x16bf16_1k(a, b, c, 0, 0, 0);
}
#else
__device__ __forceinline__ f32x4 mfma16(s16x4 a, s16x4 b, f32x4 c) {
  f32x4 d;
  asm("v_mfma_f32_16x16x16_bf16 %0, %1, %2, %3"
      : "=v"(d) : "v"(a), "v"(b), "0"(c));
  return d;
}
#endif

__device__ __forceinline__ u16 f2bf(float f) {            // RNE fp32->bf16 (scalar)
  u32 u = __builtin_bit_cast(u32, f);
  return (u16)((u + 0x7FFFu + ((u >> 16) & 1u)) >> 16);
}
__device__ __forceinline__ u32 cvtpk(float lo, float hi) { // 2xf32 -> packed bf16x2
  u32 r;
  asm("v_cvt_pk_bf16_f32 %0, %1, %2" : "=v"(r) : "v"(lo), "v"(hi));
  return r;
}
// XOR swizzle (involution) for 128B-row LDS tiles: col ^= (row&7)<<4.
__device__ __forceinline__ u32 swz128(u32 b) { return b ^ (((b >> 7) & 7u) << 4); }

// ---------------- fp32 -> bf16 convert (8 elem/thread) ----------------------
__global__ __launch_bounds__(256) void cvt_kernel(const float* __restrict__ in,
                                                  u16* __restrict__ out, float scale) {
  const size_t i = (size_t)blockIdx.x * 256 + threadIdx.x;
  f32x4 a = *(const f32x4*)(in + i * 8);
  f32x4 b = *(const f32x4*)(in + i * 8 + 4);
  u32x4 w;
  w.x = cvtpk(a[0] * scale, a[1] * scale);
  w.y = cvtpk(a[2] * scale, a[3] * scale);
  w.z = cvtpk(b[0] * scale, b[1] * scale);
  w.w = cvtpk(b[2] * scale, b[3] * scale);
  *(u32x4*)(out + i * 8) = w;
}

// ---------------- mask (int32 0/1) -> packed bits (bit=1 means masked) ------
__global__ __launch_bounds__(256) void pack_mask_kernel(const int* __restrict__ m,
                                                        u64* __restrict__ out) {
  const size_t i = (size_t)blockIdx.x * 256 + threadIdx.x;
  u64 bal = __ballot(m[i] == 1);
  if ((threadIdx.x & 63) == 0) out[i >> 6] = bal;
}

// ---------------- GEMM: C[8192][1024] = A[M][K] * W[N][K]^T, bf16 -----------
// 128x128 tile, BK=64, double-buffered LDS (one barrier per K-step).
// MODE 0: bf16 head-split  Qh[((b*16+h)*2048+s)*64+d]
// MODE 1: bf16 transposed  Vt[((b*16+h)*64+d)*2048+s]
// MODE 2: fp32 row-major   out[m*1024+n]
template <int MODE>
__global__ __launch_bounds__(256)
void gemm_bt(const u16* __restrict__ A, const u16* __restrict__ W,
             void* __restrict__ outp, int K_) {
  __shared__ alignas(16) char sm[65536];   // buf{A 16K | B 16K} x2
  const int tid = threadIdx.x, lane = tid & 63, wid = tid >> 6;
  const int g = lane >> 4, ln16 = lane & 15;
  const int wr = wid >> 1, wc = wid & 1;
  const int bm = blockIdx.y * 128, bn = blockIdx.x * 128;
  const int ldb = K_ * 2;

  // fragment base offsets (128B rows, swz128); imm offset t*2048 at use
  u32 abase[2], bbase[2];
#pragma unroll
  for (int kk = 0; kk < 2; ++kk) {
    const u32 sb = ((u32)(kk * 64 + g * 16)) ^ (((u32)ln16 & 7u) << 4);
    abase[kk] = ((u32)(wr * 64 + ln16) << 7) + sb;
    bbase[kk] = 16384u + ((u32)(wc * 64 + ln16) << 7) + sb;
  }
  // staging coords: linear LDS dest, source pre-permuted through the swizzle
  const char* ga[4]; const char* gw[4];
#pragma unroll
  for (int i = 0; i < 4; ++i) {
    u32 lb = swz128((u32)(tid + i * 256) << 4);
    u32 row = lb >> 7, kbyte = lb & 127;
    ga[i] = (const char*)A + (size_t)(bm + row) * ldb + kbyte;
    gw[i] = (const char*)W + (size_t)(bn + row) * ldb + kbyte;
  }
  f32x4 acc[4][4] = {};
  const int nk = K_ >> 6;
  int cur = 0;

#define G_STAGE(BUF)                                                  \
  {                                                                   \
    char* dst = sm + (BUF) * 32768 + wid * 1024;                      \
    _Pragma("unroll") for (int i = 0; i < 4; ++i) {                   \
      GLD16(ga[i], dst + i * 4096);                                   \
      GLD16(gw[i], dst + 16384 + i * 4096);                           \
      ga[i] += 128; gw[i] += 128;                                     \
    }                                                                 \
  }

  G_STAGE(0);
  for (int kt = 0; kt < nk; ++kt) {
    __syncthreads();                       // vmcnt(0) drain -> buf[cur] ready
    if (kt + 1 < nk) G_STAGE(cur ^ 1);     // prefetch flies under compute
    const char* cb = sm + cur * 32768;
#pragma unroll
    for (int kk = 0; kk < 2; ++kk) {
      short8 aF[4], bF[4];
#pragma unroll
      for (int t = 0; t < 4; ++t) aF[t] = *(const short8*)(cb + abase[kk] + t * 2048);
#pragma unroll
      for (int t = 0; t < 4; ++t) bF[t] = *(const short8*)(cb + bbase[kk] + t * 2048);
#pragma unroll
      for (int mt = 0; mt < 4; ++mt)
#pragma unroll
        for (int nt = 0; nt < 4; ++nt)
          acc[mt][nt] = MFMA32(aF[mt], bF[nt], acc[mt][nt]);
    }
    cur ^= 1;
  }
  // epilogue: C frag layout col=lane&15, row=(lane>>4)*4+reg  [m89-verified]
#pragma unroll
  for (int mt = 0; mt < 4; ++mt)
#pragma unroll
    for (int nt = 0; nt < 4; ++nt) {
      const f32x4 v = acc[mt][nt];
      const int row0 = bm + wr * 64 + mt * 16 + g * 4;
      const int col = bn + wc * 64 + nt * 16 + ln16;
      if (MODE == 2) {
        float* o = (float*)outp;
#pragma unroll
        for (int r = 0; r < 4; ++r) o[(size_t)(row0 + r) * 1024 + col] = v[r];
      } else if (MODE == 0) {
        u16* o = (u16*)outp;
        const int h = col >> 6, d = col & 63;
#pragma unroll
        for (int r = 0; r < 4; ++r) {
          const int row = row0 + r, b = row >> 11, s = row & 2047;
          o[((size_t)(b * 16 + h) * 2048 + s) * 64 + d] = f2bf(v[r]);
        }
      } else {  // MODE 1: transposed V; 4 consecutive s -> one 8B store
        u16* o = (u16*)outp;
        const int h = col >> 6, d = col & 63;
        const int b = row0 >> 11, s = row0 & 2047;
        u32x2 pv; pv.x = cvtpk(v[0], v[1]); pv.y = cvtpk(v[2], v[3]);
        *(u32x2*)&o[((size_t)(b * 16 + h) * 64 + d) * 2048 + s] = pv;
      }
    }
#undef G_STAGE
}

// ---------------- fused flash attention -------------------------------------
// Block: (qblk, h, b), 128 q-rows, 4 waves (32 q each). KV-tile = 64, dbuf.
// S^T = mfma_16x16x32(A=K, B=Q^T): lane(g,ln16) holds S^T[k=kt*16+g*4+r][q=ln16].
// PV via mfma_16x16x16(A=V^T, B=P^T): B-frag k=g*4+e matches S^T rows -> P is
// LANE-LOCAL (no LDS bounce, no shuffles). C/D layout shape-determined ->
// accumulator/epilogue unchanged. exp2 domain (log2e/8 folded into wq).
__global__ __launch_bounds__(256)
void attn_kernel(const u16* __restrict__ Qh, const u16* __restrict__ Kh,
                 const u16* __restrict__ Vt, const u64* __restrict__ mp,
                 u16* __restrict__ AO) {
  __shared__ alignas(16) char sm[32768];   // buf{K 8K | V 8K} x2
  const int tid = threadIdx.x, lane = tid & 63, wid = tid >> 6;
  const int g = lane >> 4, ln16 = lane & 15;
  const int h = blockIdx.y, b = blockIdx.z, bh = b * 16 + h;
  const int q0 = blockIdx.x * 128 + wid * 32;
  const u16* Qb = Qh + (size_t)bh * 2048 * 64;
  const char* Kb = (const char*)Kh + (size_t)bh * 2048 * 128;
  const char* Vb = (const char*)Vt + (size_t)bh * 64 * 4096;

  short8 qf[2][2];  // hoisted Q B-frags (16x16x32): q=ln16, d=s*32+g*8..+8
#pragma unroll
  for (int qs = 0; qs < 2; ++qs)
#pragma unroll
    for (int s = 0; s < 2; ++s)
      qf[qs][s] = *(const short8*)(Qb + (size_t)(q0 + qs * 16 + ln16) * 64 + s * 32 + g * 8);

  f32x4 acc[2][4] = {};
  float mx[2] = {-1e30f, -1e30f};
  float ls[2] = {0.f, 0.f};

  // staging coords (pre-swizzled source, linear dest)
  u32 srow[2], sbyt[2];
#pragma unroll
  for (int i = 0; i < 2; ++i) {
    u32 lb = swz128((u32)(tid + i * 256) << 4);
    srow[i] = lb >> 7; sbyt[i] = lb & 127;
  }
  // K frag LDS offsets: addr = cur*16384 + kt*2048 + kbase[s]
  u32 kbase[2];
#pragma unroll
  for (int s = 0; s < 2; ++s)
    kbase[s] = ((u32)ln16 << 7) + (((u32)(s * 64 + g * 16)) ^ (((u32)ln16 & 7u) << 4));
  // V frag LDS offsets (b64 reads): addr = cur*16384 + vbyt[kt] + dt*2048
  u32 vbyt[4];
#pragma unroll
  for (int kt = 0; kt < 4; ++kt)
    vbyt[kt] = 8192u + ((u32)ln16 << 7) + (((u32)(kt * 32 + g * 8)) ^ (((u32)ln16 & 7u) << 4));

  const u64* mq = mp + ((size_t)b * 2048 + q0 + ln16) * 32;

#define A_STAGE(KV, BUF)                                                        \
  {                                                                             \
    char* dst = sm + (BUF) * 16384 + wid * 1024;                                \
    _Pragma("unroll") for (int i = 0; i < 2; ++i) {                             \
      GLD16(Kb + (size_t)((KV) + srow[i]) * 128 + sbyt[i], dst + i * 4096);     \
      GLD16(Vb + (size_t)srow[i] * 4096 + (size_t)(KV) * 2 + sbyt[i],           \
            dst + 8192 + i * 4096);                                             \
    }                                                                           \
  }

  int cur = 0;
  A_STAGE(0, 0);
  u64 mwc0 = mq[0], mwc1 = mq[512];

  for (int kvt = 0; kvt < 32; ++kvt) {
    __syncthreads();                        // vmcnt(0) drain -> buf[cur] ready
    if (kvt + 1 < 32) A_STAGE((kvt + 1) * 64, cur ^ 1);
    const u64 mw0 = mwc0, mw1 = mwc1;
    if (kvt + 1 < 32) { mwc0 = mq[kvt + 1]; mwc1 = mq[512 + kvt + 1]; }
    const char* cb = sm + cur * 16384;

    // ---- QK^T ----
    f32x4 sc[2][4] = {};
#pragma unroll
    for (int s = 0; s < 2; ++s)
#pragma unroll
      for (int kt = 0; kt < 4; ++kt) {
        short8 kfv = *(const short8*)(cb + kt * 2048 + kbase[s]);
        sc[0][kt] = MFMA32(kfv, qf[0][s], sc[0][kt]);
        sc[1][kt] = MFMA32(kfv, qf[1][s], sc[1][kt]);
      }

    // ---- softmax (lane-local) + pack P into 16x16x16 B-frags ----
    s16x4 pb[2][4];
#pragma unroll
    for (int qs = 0; qs < 2; ++qs) {
      const u64 mw = qs ? mw1 : mw0;
      float tm = sc[qs][0][0];
#pragma unroll
      for (int kt = 0; kt < 4; ++kt)
#pragma unroll
        for (int r = 0; r < 4; ++r) tm = fmaxf(tm, sc[qs][kt][r]);
      tm = fmaxf(tm, __shfl_xor(tm, 16, 64));
      tm = fmaxf(tm, __shfl_xor(tm, 32, 64));
      const float mn = fmaxf(mx[qs], tm);
      const float corr = EXP2F(mx[qs] - mn);
      mx[qs] = mn;
      const u32 lo = (u32)mw, hi = (u32)(mw >> 32);
      float ps = 0.f;
#pragma unroll
      for (int kt = 0; kt < 4; ++kt) {
        const u32 nib = (((kt < 2) ? lo : hi) >> ((kt & 1) * 16 + g * 4)) & 0xFu;
        float p[4];
#pragma unroll
        for (int r = 0; r < 4; ++r) {
          p[r] = EXP2F(sc[qs][kt][r] - mn);
          if (nib & (1u << r)) p[r] = 0.f;
          ps += p[r];
        }
        u32x2 ww; ww.x = cvtpk(p[0], p[1]); ww.y = cvtpk(p[2], p[3]);
        pb[qs][kt] = __builtin_bit_cast(s16x4, ww);
      }
      ps += __shfl_xor(ps, 16, 64);
      ps += __shfl_xor(ps, 32, 64);
      ls[qs] = ls[qs] * corr + ps;
#pragma unroll
      for (int dt = 0; dt < 4; ++dt) acc[qs][dt] = acc[qs][dt] * corr;
    }

    // ---- PV: O^T += V^T * P^T  (16x16x16, P lane-local) ----
#pragma unroll
    for (int kt = 0; kt < 4; ++kt) {
      s16x4 vf[4];
#pragma unroll
      for (int dt = 0; dt < 4; ++dt)
        vf[dt] = *(const s16x4*)(cb + vbyt[kt] + dt * 2048);
#pragma unroll
      for (int dt = 0; dt < 4; ++dt) {
        acc[0][dt] = mfma16(vf[dt], pb[0][kt], acc[0][dt]);
        acc[1][dt] = mfma16(vf[dt], pb[1][kt], acc[1][dt]);
      }
    }
    cur ^= 1;
  }
#undef A_STAGE

#pragma unroll
  for (int qs = 0; qs < 2; ++qs) {
    const float rl = 1.0f / ls[qs];
    const int q = q0 + qs * 16 + ln16;
#pragma unroll
    for (int dt = 0; dt < 4; ++dt) {
      const f32x4 v = acc[qs][dt];
      u32x2 pv; pv.x = cvtpk(v[0] * rl, v[1] * rl); pv.y = cvtpk(v[2] * rl, v[3] * rl);
      *(u32x2*)(AO + ((size_t)b * 2048 + q) * 1024 + h * 64 + dt * 16 + g * 4) = pv;
    }
  }
}

// ---------------------------------------------------------------------------
extern "C" void kernel_launch(void* const* d_in, const int* in_sizes, int n_in,
                              void* d_out, int out_size, void* d_ws, size_t ws_size,
                              hipStream_t stream) {
  const float* q   = (const float*)d_in[0];
  const float* k   = (const float*)d_in[1];
  const float* v   = (const float*)d_in[2];
  const int*   msk = (const int*)d_in[3];
  const float* wq  = (const float*)d_in[4];
  const float* wk  = (const float*)d_in[5];
  const float* wv  = (const float*)d_in[6];
  const float* wo  = (const float*)d_in[7];

  char* ws = (char*)d_ws;
  const size_t SZX = (size_t)8192 * 1024 * 2;  // 16 MiB activation (bf16)
  const size_t SZW = (size_t)1024 * 1024 * 2;  // 2 MiB weight (bf16)
  u16* qb  = (u16*)(ws + 0 * SZX);
  u16* kb  = (u16*)(ws + 1 * SZX);
  u16* vb  = (u16*)(ws + 2 * SZX);
  u16* wqb = (u16*)(ws + 3 * SZX + 0 * SZW);
  u16* wkb = (u16*)(ws + 3 * SZX + 1 * SZW);
  u16* wvb = (u16*)(ws + 3 * SZX + 2 * SZW);
  u16* wob = (u16*)(ws + 3 * SZX + 3 * SZW);
  u16* Qh  = (u16*)(ws + 3 * SZX + 4 * SZW);
  u16* Kh  = (u16*)(ws + 4 * SZX + 4 * SZW);
  u16* Vtp = (u16*)(ws + 5 * SZX + 4 * SZW);
  u16* AO  = qb;                               // alias: qb dead after Q GEMM
  u64* mp  = (u64*)(ws + 6 * SZX + 4 * SZW);   // peak ~106 MiB

  const float QSCALE = 0.18033688011112042f;  // log2(e) / sqrt(64)

  cvt_kernel<<<4096, 256, 0, stream>>>(q, qb, 1.0f);
  cvt_kernel<<<4096, 256, 0, stream>>>(k, kb, 1.0f);
  cvt_kernel<<<4096, 256, 0, stream>>>(v, vb, 1.0f);
  cvt_kernel<<<512, 256, 0, stream>>>(wq, wqb, QSCALE);
  cvt_kernel<<<512, 256, 0, stream>>>(wk, wkb, 1.0f);
  cvt_kernel<<<512, 256, 0, stream>>>(wv, wvb, 1.0f);
  cvt_kernel<<<512, 256, 0, stream>>>(wo, wob, 1.0f);
  pack_mask_kernel<<<65536, 256, 0, stream>>>(msk, mp);

  gemm_bt<0><<<dim3(8, 64), 256, 0, stream>>>(qb, wqb, (void*)Qh, 1024);
  gemm_bt<0><<<dim3(8, 64), 256, 0, stream>>>(kb, wkb, (void*)Kh, 1024);
  gemm_bt<1><<<dim3(8, 64), 256, 0, stream>>>(vb, wvb, (void*)Vtp, 1024);

  attn_kernel<<<dim3(16, 16, 4), 256, 0, stream>>>(Qh, Kh, Vtp, mp, AO);

  gemm_bt<2><<<dim3(8, 64), 256, 0, stream>>>(AO, wob, d_out, 1024);
}